// Round 13
// baseline (221.392 us; speedup 1.0000x reference)
//
#include <hip/hip_runtime.h>
#include <hip/hip_bf16.h>

// ---------------------------------------------------------------------------
// OutliersQLinearColumn: out = x @ w^T + bias,  w = s_o*sign(weight-mean_o)
// with fp32 outlier columns scattered in (last-wins).
// Round 13: occupancy round. 128x128 tile, 256 thr (4 waves of 64x64 output),
// 3 LDS bufs x 16 KB (48 KB/block) -> 3 independent blocks/CU (3 waves/SIMD,
// reg budget 170: acc 64 + ~46 arch). Cross-block TLP overlaps one block's
// LDS reads/stages with another's MFMAs (m114) -- the proven-additive
// MFMA+LDS wall (R12: 74+56=130us measured) collapses toward max(...).
// Same slot-XOR swizzle (measured 0 conflicts), vmcnt(4) 2-tile pipeline.
// 2D XCD chunking (32bm x 8bn) keeps the B working set L2-resident.
// ---------------------------------------------------------------------------

typedef __attribute__((ext_vector_type(4))) int i32x4;

// ---------------------------------------------------------------------------
// Weight row -> mean, scale, qw = 8*sign (main) + correction cols.
// colmap (last-wins winner per column) rebuilt per block in LDS.
// ---------------------------------------------------------------------------
__global__ void quant_sign_kernel(const float* __restrict__ w,
                                  const float* __restrict__ ow,
                                  const int* __restrict__ idx,
                                  signed char* __restrict__ qw,
                                  float* __restrict__ sArr,
                                  int IC, int K2, int n_out) {
    __shared__ float red[8];
    __shared__ signed char sgn[4096];
    __shared__ int cmL[4096];
    const int o = blockIdx.x;
    const int t = threadIdx.x;
    const int lane = t & 63, wid = t >> 6;

#pragma unroll
    for (int i = 0; i < 16; ++i) cmL[t + i * 256] = -1;

    const float4* row4 = (const float4*)(w + (size_t)o * IC);
    float4 v[4];
    float s = 0.f;
#pragma unroll
    for (int j = 0; j < 4; ++j) {
        v[j] = row4[t + j * 256];
        s += v[j].x + v[j].y + v[j].z + v[j].w;
    }
#pragma unroll
    for (int off = 32; off; off >>= 1) s += __shfl_down(s, off);
    if (lane == 0) red[wid] = s;
    __syncthreads();
    const float mean = (red[0] + red[1] + red[2] + red[3]) / (float)IC;

    if (t < n_out) atomicMax(&cmL[idx[t]], t);

    float a = 0.f;
#pragma unroll
    for (int j = 0; j < 4; ++j)
        a += fabsf(v[j].x - mean) + fabsf(v[j].y - mean) +
             fabsf(v[j].z - mean) + fabsf(v[j].w - mean);
#pragma unroll
    for (int off = 32; off; off >>= 1) a += __shfl_down(a, off);
    if (lane == 0) red[4 + wid] = a;
    __syncthreads();
    const float scale = (red[4] + red[5] + red[6] + red[7]) / (float)IC;
    if (t == 0) sArr[o] = scale;

    const size_t base = (size_t)o * K2;
#pragma unroll
    for (int j = 0; j < 4; ++j) {
        const int c0 = (t + j * 256) * 4;
        float ee[4] = {v[j].x, v[j].y, v[j].z, v[j].w};
        int pack = 0;
#pragma unroll
        for (int ei = 0; ei < 4; ++ei) {
            float c = ee[ei] - mean;
            int q = c > 0.f ? 8 : (c < 0.f ? -8 : 0);
            pack |= (q & 0xff) << (ei * 8);
        }
        *(int*)(qw + base + c0) = pack;
        *(int*)(sgn + c0) = pack;
    }
    __syncthreads();

    signed char q = 0;
    if (t < n_out) {
        const int c = idx[t];
        if (cmL[c] == t) {
            const float sg = (float)sgn[c] * 0.125f;   // +-1 or 0
            const float wc = ow[(size_t)o * n_out + t] - scale * sg;
            float qf = rintf(8.f * wc / scale);
            qf = fminf(127.f, fmaxf(-127.f, qf));
            q = (signed char)(int)qf;
        }
    }
    qw[base + IC + t] = q;
}

// ---------------------------------------------------------------------------
// x row -> D_m, qx = rint(x/D_m) (main) + gathered correction cols (fused).
// ---------------------------------------------------------------------------
__global__ void quant_x_kernel(const float4* __restrict__ x4,
                               const int* __restrict__ idx,
                               signed char* __restrict__ qx,
                               float* __restrict__ rdel,
                               int IC, int K2, int n_out) {
    __shared__ float red[4];
    __shared__ float bmax;
    __shared__ signed char rowq[4096];
    const int m = blockIdx.x;
    const int t = threadIdx.x;
    const int lane = t & 63, wid = t >> 6;

    const float4* row4 = x4 + (size_t)m * (IC / 4);
    float4 v[4];
    float mx = 0.f;
#pragma unroll
    for (int j = 0; j < 4; ++j) {
        v[j] = row4[t + j * 256];
        mx = fmaxf(mx, fmaxf(fmaxf(fabsf(v[j].x), fabsf(v[j].y)),
                             fmaxf(fabsf(v[j].z), fabsf(v[j].w))));
    }
#pragma unroll
    for (int off = 32; off; off >>= 1) mx = fmaxf(mx, __shfl_down(mx, off));
    if (lane == 0) red[wid] = mx;
    __syncthreads();
    if (t == 0) {
        float m0 = fmaxf(fmaxf(red[0], red[1]), fmaxf(red[2], red[3]));
        bmax = m0;
        rdel[m] = m0 / 127.f;
    }
    __syncthreads();
    const float inv = 127.f / bmax;

    const size_t base = (size_t)m * K2;
#pragma unroll
    for (int j = 0; j < 4; ++j) {
        const int c0 = (t + j * 256) * 4;
        float ee[4] = {v[j].x, v[j].y, v[j].z, v[j].w};
        int pack = 0;
#pragma unroll
        for (int ei = 0; ei < 4; ++ei) {
            int q = (int)rintf(ee[ei] * inv);
            pack |= (q & 0xff) << (ei * 8);
        }
        *(int*)(qx + base + c0) = pack;
        *(int*)(rowq + c0) = pack;
    }
    __syncthreads();

    signed char g = 0;
    if (t < n_out) g = rowq[idx[t]];
    qx[base + IC + t] = g;
}

// ---------------------------------------------------------------------------
// i8 GEMM: acc[m,o] = sum_k qx[m,k]*qw[o,k]; out = acc*(s_o*D_m/8) + bias.
// 256 thr = 4 waves (2M x 2N), per-wave 64x64 = 4(mi) x 4(ni) frags 16x16,
// mfma_i32_16x16x64_i8 (16 MFMA/wave/tile, one K-phase per tile).
// LDS: 3 bufs x (A 8 KB + B 8 KB), slot-XOR swizzle (0 conflicts).
// Per tile: { RDB(4)+RDA(4) from buf t%3 ; stage tile t+2 -> buf (t+2)%3
//             (4 x global_load_lds) ; vmcnt(4) ; barrier ;
//             setprio(1) ; 16 MFMA ; setprio(0) ; barrier }
// vmcnt(4): keeps t+2's 4 loads in flight, drains t+1 (issued 1 tile ago).
// WAR: buf (t+2)%3 == buf (t-1)%3 whose reads completed before the end-of-
// (t-1) barrier. Cross-block overlap: 3 blocks/CU, no shared barriers.
// ---------------------------------------------------------------------------
#define GLDS(src, dst) __builtin_amdgcn_global_load_lds( \
    (const __attribute__((address_space(1))) void*)(src), \
    (__attribute__((address_space(3))) void*)(dst), 16, 0, 0)

// Stage rows RR*64.. of matrix MAT of the tile at byte k-offset knB -> bufS.
#define STG1(MAT, bufS, knB, RR) \
    GLDS((((MAT) ? Bblk : Ablk) + (size_t)((RR) * 64 + stg_row) * K2 + (knB) + stg_col), \
         &ldsb[(bufS) * 16384 + (MAT) * 8192 + ((RR) * 64 + wid * 16) * 64])

#define RDA(B_) do {                                                          \
    const signed char* pa_ = &ldsb[(B_) * 16384];                             \
    _Pragma("unroll")                                                         \
    for (int j_ = 0; j_ < 4; ++j_)                                            \
      afr[j_] = *(const i32x4*)&pa_[(wr * 64 + j_ * 16 + l15) * 64 + slB];    \
  } while (0)

#define RDB(B_) do {                                                          \
    const signed char* pb_ = &ldsb[(B_) * 16384 + 8192];                      \
    _Pragma("unroll")                                                         \
    for (int j_ = 0; j_ < 4; ++j_)                                            \
      bfr[j_] = *(const i32x4*)&pb_[(wc * 64 + j_ * 16 + l15) * 64 + slB];    \
  } while (0)

#define MM16() do {                                                           \
    _Pragma("unroll")                                                         \
    for (int mi_ = 0; mi_ < 4; ++mi_)                                         \
      _Pragma("unroll")                                                       \
      for (int ni_ = 0; ni_ < 4; ++ni_)                                       \
        acc[mi_][ni_] = __builtin_amdgcn_mfma_i32_16x16x64_i8(                \
            afr[mi_], bfr[ni_], acc[mi_][ni_], 0, 0, 0);                      \
  } while (0)

#define KT(bufR, bufS, knB) do {                                              \
    RDB(bufR);                                                                \
    RDA(bufR);                                                                \
    STG1(0, bufS, knB, 0); STG1(0, bufS, knB, 1);                             \
    STG1(1, bufS, knB, 0); STG1(1, bufS, knB, 1);                             \
    asm volatile("s_waitcnt vmcnt(4)" ::: "memory");                          \
    __builtin_amdgcn_s_barrier();                                             \
    __builtin_amdgcn_s_setprio(1);                                            \
    MM16();                                                                   \
    __builtin_amdgcn_s_setprio(0);                                            \
    __builtin_amdgcn_s_barrier();                                             \
  } while (0)

__global__ __launch_bounds__(256, 3) void gemm_i8_kernel(
    const signed char* __restrict__ Aq,   // [M, K2] i8
    const signed char* __restrict__ Bq,   // [OC, K2] i8
    const float* __restrict__ bias,       // [OC]
    const float* __restrict__ sArr,       // [OC]
    const float* __restrict__ rdel,       // [M]
    float* __restrict__ C,                // [M, OC] f32
    int M, int N, int K2, int NBM, int NBN) {
    extern __shared__ signed char ldsb[];  // 49152 B = 3 bufs x 16 KiB

    const int t = threadIdx.x;
    const int wid = t >> 6, lane = t & 63;
    const int l15 = lane & 15;
    const int slB = (((lane >> 4) ^ ((lane >> 1) & 3)) & 3) * 16;  // read slot
    const int wr = wid >> 1;                  // 0..1 (M half)
    const int wc = wid & 1;                   // 0..1 (N half)
    const int stg_row = wid * 16 + (lane >> 2);
    const int stg_col = (((lane & 3) ^ ((lane >> 3) & 3)) & 3) * 16;  // bytes

    // 2D XCD chunking: 8 chunks of 32bm x 8bn (B-chunk 4.4 MB ~ L2-resident,
    // 8 blocks per bm-row share an A panel). Fallback: bijective 1D swizzle.
    const int bid = blockIdx.x;
    int bm, bn;
    if ((NBM & 31) == 0 && (NBN & 7) == 0 && (NBM >> 5) * (NBN >> 3) == 8) {
        const int xcd = bid & 7, loc = bid >> 3;
        bm = (xcd >> 2) * 32 + (loc >> 3);
        bn = (xcd & 3) * 8 + (loc & 7);
    } else {
        const int nwg = gridDim.x;
        const int q = nwg >> 3, r = nwg & 7;
        const int xcd = bid & 7, off = bid >> 3;
        const int swz = (xcd < r ? xcd * (q + 1) : r * (q + 1) + (xcd - r) * q) + off;
        bm = swz / NBN; bn = swz % NBN;
    }

    const signed char* Ablk = Aq + (size_t)(bm * 128) * K2;
    const signed char* Bblk = Bq + (size_t)(bn * 128) * K2;

    i32x4 acc[4][4] = {};
    i32x4 afr[4], bfr[4];

    // ---- prologue: stage tiles 0 -> buf0, 1 -> buf1; drain tile0 ----
    STG1(0, 0, 0, 0);  STG1(0, 0, 0, 1);  STG1(1, 0, 0, 0);  STG1(1, 0, 0, 1);
    STG1(0, 1, 64, 0); STG1(0, 1, 64, 1); STG1(1, 1, 64, 0); STG1(1, 1, 64, 1);
    asm volatile("s_waitcnt vmcnt(4)" ::: "memory");
    __builtin_amdgcn_s_barrier();

    // 68 tiles = 22 iterations x 3 + 2 tail. Tile t: read buf t%3,
    // stage tile t+2 -> buf (t+2)%3.
    for (int it = 0; it < 22; ++it) {
        const int tt = it * 3;
        const int ka = (tt + 2) * 64;                        // <= 67*64, live
        const int kb = (tt + 3 < 68) ? (tt + 3) * 64 : 0;
        const int kc = (tt + 4 < 68) ? (tt + 4) * 64 : 0;
        KT(0, 2, ka);
        KT(1, 0, kb);
        KT(2, 1, kc);
    }
    KT(0, 2, 0);   // tile 66 (dead stage)
    KT(1, 0, 0);   // tile 67 (dead stage)

    // ---- epilogue: out = acc*(s_o*D_m/8) + bias ----
    // C/D layout: col = lane&15, row = (lane>>4)*4 + reg
    float sv[4], bv[4];
#pragma unroll
    for (int ni = 0; ni < 4; ++ni) {
        const int col = bn * 128 + wc * 64 + ni * 16 + l15;
        sv[ni] = sArr[col] * 0.125f;
        bv[ni] = bias[col];
    }

    const int crow0 = bm * 128 + wr * 64;
    const int ccol = bn * 128 + wc * 64 + l15;
#pragma unroll
    for (int mi = 0; mi < 4; ++mi) {
#pragma unroll
        for (int rr = 0; rr < 4; ++rr) {
            const int row = crow0 + mi * 16 + (lane >> 4) * 4 + rr;
            const float rd = rdel[row];
            float* Crow = C + (size_t)row * N;
#pragma unroll
            for (int ni = 0; ni < 4; ++ni)
                Crow[ccol + ni * 16] =
                    (float)acc[mi][ni][rr] * (sv[ni] * rd) + bv[ni];
        }
    }
}

// ---------------------------------------------------------------------------
extern "C" void kernel_launch(void* const* d_in, const int* in_sizes, int n_in,
                              void* d_out, int out_size, void* d_ws, size_t ws_size,
                              hipStream_t stream) {
    const float* x      = (const float*)d_in[0];
    const float* weight = (const float*)d_in[1];
    const float* bias   = (const float*)d_in[2];
    const float* ow     = (const float*)d_in[3];
    const int*   idx    = (const int*)d_in[4];

    const int OC    = in_sizes[2];
    const int n_out = in_sizes[4];
    const int IC    = in_sizes[1] / OC;      // 4096
    const int M     = in_sizes[0] / IC;      // 8192
    const int K2    = IC + 256;              // 4352
    float* out = (float*)d_out;

    char* ws = (char*)d_ws;
    signed char* qx = (signed char*)ws;                                 // M*K2
    signed char* qw = (signed char*)(ws + (size_t)M * K2);              // OC*K2
    float* sArr = (float*)(ws + (size_t)M * K2 + (size_t)OC * K2);      // OC
    float* rdel = sArr + OC;                                            // M

    quant_sign_kernel<<<OC, 256, 0, stream>>>(weight, ow, idx, qw, sArr,
                                              IC, K2, n_out);
    quant_x_kernel<<<M, 256, 0, stream>>>((const float4*)x, idx, qx, rdel,
                                          IC, K2, n_out);

    hipFuncSetAttribute((const void*)gemm_i8_kernel,
                        hipFuncAttributeMaxDynamicSharedMemorySize, 49152);
    const int NBM = M / 128, NBN = OC / 128;
    gemm_i8_kernel<<<dim3(NBM * NBN), dim3(256), 49152, stream>>>(
        qx, qw, bias, sArr, rdel, out, M, OC, K2, NBM, NBN);
}

// Round 14
// 181.130 us; speedup vs baseline: 1.2223x; 1.2223x over previous
//
#include <hip/hip_runtime.h>
#include <hip/hip_bf16.h>

// ---------------------------------------------------------------------------
// OutliersQLinearColumn: out = x @ w^T + bias,  w = s_o*sign(weight-mean_o)
// with fp32 outlier columns scattered in (last-wins).
// Round 14: R12 GEMM (256x256, 8 waves, 4 bufs, vmcnt(8)) with the tile's
// FULL read batch issued upfront (RDB + RDA0 + RDA1, 12 ds_read_b128) so
// MFMA0 runs under counted lgkmcnt(4) while RDA1 completes in its shadow --
// removes the second serialized LDS round-trip from each wave's chain.
// Single tile-end barrier (visibility via vmcnt(8); WAR via read-before-
// MFMA1-before-barrier). Prep: R12's fused 2-kernel version.
// ---------------------------------------------------------------------------

typedef __attribute__((ext_vector_type(4))) int i32x4;

// ---------------------------------------------------------------------------
// Weight row -> mean, scale, qw = 8*sign (main) + correction cols.
// colmap (last-wins winner per column) rebuilt per block in LDS.
// ---------------------------------------------------------------------------
__global__ void quant_sign_kernel(const float* __restrict__ w,
                                  const float* __restrict__ ow,
                                  const int* __restrict__ idx,
                                  signed char* __restrict__ qw,
                                  float* __restrict__ sArr,
                                  int IC, int K2, int n_out) {
    __shared__ float red[8];
    __shared__ signed char sgn[4096];
    __shared__ int cmL[4096];
    const int o = blockIdx.x;
    const int t = threadIdx.x;
    const int lane = t & 63, wid = t >> 6;

#pragma unroll
    for (int i = 0; i < 16; ++i) cmL[t + i * 256] = -1;

    const float4* row4 = (const float4*)(w + (size_t)o * IC);
    float4 v[4];
    float s = 0.f;
#pragma unroll
    for (int j = 0; j < 4; ++j) {
        v[j] = row4[t + j * 256];
        s += v[j].x + v[j].y + v[j].z + v[j].w;
    }
#pragma unroll
    for (int off = 32; off; off >>= 1) s += __shfl_down(s, off);
    if (lane == 0) red[wid] = s;
    __syncthreads();
    const float mean = (red[0] + red[1] + red[2] + red[3]) / (float)IC;

    if (t < n_out) atomicMax(&cmL[idx[t]], t);

    float a = 0.f;
#pragma unroll
    for (int j = 0; j < 4; ++j)
        a += fabsf(v[j].x - mean) + fabsf(v[j].y - mean) +
             fabsf(v[j].z - mean) + fabsf(v[j].w - mean);
#pragma unroll
    for (int off = 32; off; off >>= 1) a += __shfl_down(a, off);
    if (lane == 0) red[4 + wid] = a;
    __syncthreads();
    const float scale = (red[4] + red[5] + red[6] + red[7]) / (float)IC;
    if (t == 0) sArr[o] = scale;

    const size_t base = (size_t)o * K2;
#pragma unroll
    for (int j = 0; j < 4; ++j) {
        const int c0 = (t + j * 256) * 4;
        float ee[4] = {v[j].x, v[j].y, v[j].z, v[j].w};
        int pack = 0;
#pragma unroll
        for (int ei = 0; ei < 4; ++ei) {
            float c = ee[ei] - mean;
            int q = c > 0.f ? 8 : (c < 0.f ? -8 : 0);
            pack |= (q & 0xff) << (ei * 8);
        }
        *(int*)(qw + base + c0) = pack;
        *(int*)(sgn + c0) = pack;
    }
    __syncthreads();

    signed char q = 0;
    if (t < n_out) {
        const int c = idx[t];
        if (cmL[c] == t) {
            const float sg = (float)sgn[c] * 0.125f;   // +-1 or 0
            const float wc = ow[(size_t)o * n_out + t] - scale * sg;
            float qf = rintf(8.f * wc / scale);
            qf = fminf(127.f, fmaxf(-127.f, qf));
            q = (signed char)(int)qf;
        }
    }
    qw[base + IC + t] = q;
}

// ---------------------------------------------------------------------------
// x row -> D_m, qx = rint(x/D_m) (main) + gathered correction cols (fused).
// ---------------------------------------------------------------------------
__global__ void quant_x_kernel(const float4* __restrict__ x4,
                               const int* __restrict__ idx,
                               signed char* __restrict__ qx,
                               float* __restrict__ rdel,
                               int IC, int K2, int n_out) {
    __shared__ float red[4];
    __shared__ float bmax;
    __shared__ signed char rowq[4096];
    const int m = blockIdx.x;
    const int t = threadIdx.x;
    const int lane = t & 63, wid = t >> 6;

    const float4* row4 = x4 + (size_t)m * (IC / 4);
    float4 v[4];
    float mx = 0.f;
#pragma unroll
    for (int j = 0; j < 4; ++j) {
        v[j] = row4[t + j * 256];
        mx = fmaxf(mx, fmaxf(fmaxf(fabsf(v[j].x), fabsf(v[j].y)),
                             fmaxf(fabsf(v[j].z), fabsf(v[j].w))));
    }
#pragma unroll
    for (int off = 32; off; off >>= 1) mx = fmaxf(mx, __shfl_down(mx, off));
    if (lane == 0) red[wid] = mx;
    __syncthreads();
    if (t == 0) {
        float m0 = fmaxf(fmaxf(red[0], red[1]), fmaxf(red[2], red[3]));
        bmax = m0;
        rdel[m] = m0 / 127.f;
    }
    __syncthreads();
    const float inv = 127.f / bmax;

    const size_t base = (size_t)m * K2;
#pragma unroll
    for (int j = 0; j < 4; ++j) {
        const int c0 = (t + j * 256) * 4;
        float ee[4] = {v[j].x, v[j].y, v[j].z, v[j].w};
        int pack = 0;
#pragma unroll
        for (int ei = 0; ei < 4; ++ei) {
            int q = (int)rintf(ee[ei] * inv);
            pack |= (q & 0xff) << (ei * 8);
        }
        *(int*)(qx + base + c0) = pack;
        *(int*)(rowq + c0) = pack;
    }
    __syncthreads();

    signed char g = 0;
    if (t < n_out) g = rowq[idx[t]];
    qx[base + IC + t] = g;
}

// ---------------------------------------------------------------------------
// i8 GEMM: acc[m,o] = sum_k qx[m,k]*qw[o,k]; out = acc*(s_o*D_m/8) + bias.
// 512 thr = 8 waves (2M x 4N), per-wave 128x64 = 8(mi) x 4(ni) frags 16x16,
// mfma_i32_16x16x64_i8. LDS: 4 bufs x 32 KB, slot-XOR swizzle (0 conflicts).
// Per tile (1 barrier):
//   { RDB(4)+RDA0(4)+RDA1(4)  [all 12 reads upfront, buf t%4] ;
//     stage A,B of tile t+3 -> buf (t+3)%4 ;
//     MFMA0 (lgkmcnt(4): RDA1 completes in shadow) ; MFMA1 ;
//     vmcnt(8) ; barrier }
// Visibility: vmcnt(8)+barrier at tile t end drains t+1's stages before its
// reads (tile t+1 start).  WAR: reads of buf t%4 are register-complete
// before MFMA1, which precedes the barrier; the overwrite of buf t%4
// (staging t+4, in tile t+1) is issued only after that barrier.
// ---------------------------------------------------------------------------
#define GLDS(src, dst) __builtin_amdgcn_global_load_lds( \
    (const __attribute__((address_space(1))) void*)(src), \
    (__attribute__((address_space(3))) void*)(dst), 16, 0, 0)

// Stage matrix MAT (0=A,1=B) of the BK64 tile at byte k-offset knB into bufS.
#define STAGE64(MAT, bufS, knB) do {                                          \
    const signed char* gsrc_ = (MAT) ? Bblk : Ablk;                           \
    _Pragma("unroll")                                                         \
    for (int rr_ = 0; rr_ < 2; ++rr_) {                                       \
      GLDS(gsrc_ + (size_t)(rr_ * 128 + stg_row) * K2 + (knB) + stg_col,      \
           &ldsb[(bufS) * 32768 + (MAT) * 16384 + (rr_ * 128 + wid * 16) * 64]); \
    } } while (0)

// A-fragment reads (4 x ds_read_b128) for fragment-half FH from buf B_
#define RDA(AF, FH, B_) do {                                                  \
    const signed char* pa_ = &ldsb[(B_) * 32768];                             \
    _Pragma("unroll")                                                         \
    for (int j_ = 0; j_ < 4; ++j_)                                            \
      AF[j_] = *(const i32x4*)&pa_[(wr * 128 + ((FH) * 4 + j_) * 16 + l15) * 64 + slB]; \
  } while (0)

// B-fragment reads (4 x ds_read_b128) from buf B_
#define RDB(BF, B_) do {                                                      \
    const signed char* pb_ = &ldsb[(B_) * 32768 + 16384];                     \
    _Pragma("unroll")                                                         \
    for (int j_ = 0; j_ < 4; ++j_)                                            \
      BF[j_] = *(const i32x4*)&pb_[(wc * 64 + j_ * 16 + l15) * 64 + slB];     \
  } while (0)

#define MM16(AF, FH) do {                                                     \
    _Pragma("unroll")                                                         \
    for (int mi_ = 0; mi_ < 4; ++mi_)                                         \
      _Pragma("unroll")                                                       \
      for (int ni_ = 0; ni_ < 4; ++ni_)                                       \
        acc[(FH) * 4 + mi_][ni_] = __builtin_amdgcn_mfma_i32_16x16x64_i8(     \
            AF[mi_], bfr[ni_], acc[(FH) * 4 + mi_][ni_], 0, 0, 0);            \
  } while (0)

// One K-tile, all reads upfront, 1 barrier.
#define KT64(bufR, bufS, knB) do {                                            \
    RDB(bfr, bufR);                                                           \
    RDA(afr0, 0, bufR);                                                       \
    RDA(afr1, 1, bufR);                                                       \
    STAGE64(0, bufS, knB);                                                    \
    STAGE64(1, bufS, knB);                                                    \
    __builtin_amdgcn_s_setprio(1);                                            \
    MM16(afr0, 0);                                                            \
    MM16(afr1, 1);                                                            \
    __builtin_amdgcn_s_setprio(0);                                            \
    asm volatile("s_waitcnt vmcnt(8)" ::: "memory");                          \
    __builtin_amdgcn_s_barrier();                                             \
  } while (0)

__global__ __launch_bounds__(512, 2) void gemm_i8_kernel(
    const signed char* __restrict__ Aq,   // [M, K2] i8
    const signed char* __restrict__ Bq,   // [OC, K2] i8
    const float* __restrict__ bias,       // [OC]
    const float* __restrict__ sArr,       // [OC]
    const float* __restrict__ rdel,       // [M]
    float* __restrict__ C,                // [M, OC] f32
    int M, int N, int K2, int NBN) {
    extern __shared__ signed char ldsb[];  // 131072 B = 4 x 32 KiB buffers

    const int t = threadIdx.x;
    const int wid = t >> 6, lane = t & 63;
    const int l15 = lane & 15;
    const int slB = (((lane >> 4) ^ ((lane >> 1) & 3)) & 3) * 16;  // read slot
    const int wr = wid >> 2;                  // 0..1  (M half)
    const int wc = wid & 3;                   // 0..3  (N quarter)
    const int stg_row = wid * 16 + (lane >> 2);
    const int stg_col = (((lane & 3) ^ ((lane >> 3) & 3)) & 3) * 16;  // bytes

    // bijective XCD swizzle
    const int nwg = gridDim.x;
    const int bid = blockIdx.x;
    const int q = nwg >> 3, r = nwg & 7;
    const int xcd = bid & 7, off = bid >> 3;
    const int swz = (xcd < r ? xcd * (q + 1) : r * (q + 1) + (xcd - r) * q) + off;
    const int bm = swz / NBN, bn = swz % NBN;

    const signed char* Ablk = Aq + (size_t)(bm * 256) * K2;
    const signed char* Bblk = Bq + (size_t)(bn * 256) * K2;

    i32x4 acc[8][4] = {};
    i32x4 afr0[4], afr1[4], bfr[4];

    // ---- prologue: stage tiles 0,1,2 -> bufs 0,1,2; wait tile0 ----
    STAGE64(0, 0, 0);    STAGE64(1, 0, 0);
    STAGE64(0, 1, 64);   STAGE64(1, 1, 64);
    STAGE64(0, 2, 128);  STAGE64(1, 2, 128);
    asm volatile("s_waitcnt vmcnt(8)" ::: "memory");
    __builtin_amdgcn_s_barrier();

    // NT = K2/64 = 68 tiles = 17 iterations x 4. During tile t stage t+3.
    for (int it = 0; it < 17; ++it) {
        const int tt = it * 4;
        const int k3 = (tt + 3) * 64;                        // <= 67*64, live
        const int k4 = (tt + 4 < 68) ? (tt + 4) * 64 : 0;    // dead at end
        const int k5 = (tt + 5 < 68) ? (tt + 5) * 64 : 0;
        const int k6 = (tt + 6 < 68) ? (tt + 6) * 64 : 0;
        KT64(0, 3, k3);
        KT64(1, 0, k4);
        KT64(2, 1, k5);
        KT64(3, 2, k6);
    }

    // ---- epilogue: out = acc*(s_o*D_m/8) + bias ----
    // C/D layout: col = lane&15, row = (lane>>4)*4 + reg
    float sv[4], bv[4];
#pragma unroll
    for (int ni = 0; ni < 4; ++ni) {
        const int col = bn * 256 + wc * 64 + ni * 16 + l15;
        sv[ni] = sArr[col] * 0.125f;
        bv[ni] = bias[col];
    }

    const int crow0 = bm * 256 + wr * 128;
    const int ccol = bn * 256 + wc * 64 + l15;
#pragma unroll
    for (int mi = 0; mi < 8; ++mi) {
#pragma unroll
        for (int rr = 0; rr < 4; ++rr) {
            const int row = crow0 + mi * 16 + (lane >> 4) * 4 + rr;
            const float rd = rdel[row];
            float* Crow = C + (size_t)row * N;
#pragma unroll
            for (int ni = 0; ni < 4; ++ni)
                Crow[ccol + ni * 16] =
                    (float)acc[mi][ni][rr] * (sv[ni] * rd) + bv[ni];
        }
    }
}

// ---------------------------------------------------------------------------
extern "C" void kernel_launch(void* const* d_in, const int* in_sizes, int n_in,
                              void* d_out, int out_size, void* d_ws, size_t ws_size,
                              hipStream_t stream) {
    const float* x      = (const float*)d_in[0];
    const float* weight = (const float*)d_in[1];
    const float* bias   = (const float*)d_in[2];
    const float* ow     = (const float*)d_in[3];
    const int*   idx    = (const int*)d_in[4];

    const int OC    = in_sizes[2];
    const int n_out = in_sizes[4];
    const int IC    = in_sizes[1] / OC;      // 4096
    const int M     = in_sizes[0] / IC;      // 8192
    const int K2    = IC + 256;              // 4352
    float* out = (float*)d_out;

    char* ws = (char*)d_ws;
    signed char* qx = (signed char*)ws;                                 // M*K2
    signed char* qw = (signed char*)(ws + (size_t)M * K2);              // OC*K2
    float* sArr = (float*)(ws + (size_t)M * K2 + (size_t)OC * K2);      // OC
    float* rdel = sArr + OC;                                            // M

    quant_sign_kernel<<<OC, 256, 0, stream>>>(weight, ow, idx, qw, sArr,
                                              IC, K2, n_out);
    quant_x_kernel<<<M, 256, 0, stream>>>((const float4*)x, idx, qx, rdel,
                                          IC, K2, n_out);

    hipFuncSetAttribute((const void*)gemm_i8_kernel,
                        hipFuncAttributeMaxDynamicSharedMemorySize, 131072);
    const int NBM = M / 256, NBN = OC / 256;
    gemm_i8_kernel<<<dim3(NBM * NBN), dim3(512), 131072, stream>>>(
        qx, qw, bias, sArr, rdel, out, M, OC, K2, NBN);
}

// Round 15
// 178.457 us; speedup vs baseline: 1.2406x; 1.0150x over previous
//
#include <hip/hip_runtime.h>
#include <hip/hip_bf16.h>

// ---------------------------------------------------------------------------
// OutliersQLinearColumn: out = x @ w^T + bias,  w = s_o*sign(weight-mean_o)
// with fp32 outlier columns scattered in (last-wins).
// Round 15: shadow-read schedule. Tile body:
//   { STAGE(t+3) ; vmcnt(8) ; barrier ; 32 MFMA(t) ; 12 READS(t+1) }
// Reads for tile t+1 issue under tile t's MFMA pipe drain (buf t+1 is
// formally visible: its stages drained at tile t-1's vmcnt(8), barrier
// crossed). Single-buffered frag regs (MFMA frees operands at issue).
// One barrier/tile. Everything else = R12 (proven 130us): 256x256, 8 waves,
// mfma_i32_16x16x64_i8, 4 bufs x 32 KB, slot-XOR swizzle (0 conflicts).
// ---------------------------------------------------------------------------

typedef __attribute__((ext_vector_type(4))) int i32x4;

// ---------------------------------------------------------------------------
// Weight row -> mean, scale, qw = 8*sign (main) + correction cols.
// colmap (last-wins winner per column) rebuilt per block in LDS.
// ---------------------------------------------------------------------------
__global__ void quant_sign_kernel(const float* __restrict__ w,
                                  const float* __restrict__ ow,
                                  const int* __restrict__ idx,
                                  signed char* __restrict__ qw,
                                  float* __restrict__ sArr,
                                  int IC, int K2, int n_out) {
    __shared__ float red[8];
    __shared__ signed char sgn[4096];
    __shared__ int cmL[4096];
    const int o = blockIdx.x;
    const int t = threadIdx.x;
    const int lane = t & 63, wid = t >> 6;

#pragma unroll
    for (int i = 0; i < 16; ++i) cmL[t + i * 256] = -1;

    const float4* row4 = (const float4*)(w + (size_t)o * IC);
    float4 v[4];
    float s = 0.f;
#pragma unroll
    for (int j = 0; j < 4; ++j) {
        v[j] = row4[t + j * 256];
        s += v[j].x + v[j].y + v[j].z + v[j].w;
    }
#pragma unroll
    for (int off = 32; off; off >>= 1) s += __shfl_down(s, off);
    if (lane == 0) red[wid] = s;
    __syncthreads();
    const float mean = (red[0] + red[1] + red[2] + red[3]) / (float)IC;

    if (t < n_out) atomicMax(&cmL[idx[t]], t);

    float a = 0.f;
#pragma unroll
    for (int j = 0; j < 4; ++j)
        a += fabsf(v[j].x - mean) + fabsf(v[j].y - mean) +
             fabsf(v[j].z - mean) + fabsf(v[j].w - mean);
#pragma unroll
    for (int off = 32; off; off >>= 1) a += __shfl_down(a, off);
    if (lane == 0) red[4 + wid] = a;
    __syncthreads();
    const float scale = (red[4] + red[5] + red[6] + red[7]) / (float)IC;
    if (t == 0) sArr[o] = scale;

    const size_t base = (size_t)o * K2;
#pragma unroll
    for (int j = 0; j < 4; ++j) {
        const int c0 = (t + j * 256) * 4;
        float ee[4] = {v[j].x, v[j].y, v[j].z, v[j].w};
        int pack = 0;
#pragma unroll
        for (int ei = 0; ei < 4; ++ei) {
            float c = ee[ei] - mean;
            int q = c > 0.f ? 8 : (c < 0.f ? -8 : 0);
            pack |= (q & 0xff) << (ei * 8);
        }
        *(int*)(qw + base + c0) = pack;
        *(int*)(sgn + c0) = pack;
    }
    __syncthreads();

    signed char q = 0;
    if (t < n_out) {
        const int c = idx[t];
        if (cmL[c] == t) {
            const float sg = (float)sgn[c] * 0.125f;   // +-1 or 0
            const float wc = ow[(size_t)o * n_out + t] - scale * sg;
            float qf = rintf(8.f * wc / scale);
            qf = fminf(127.f, fmaxf(-127.f, qf));
            q = (signed char)(int)qf;
        }
    }
    qw[base + IC + t] = q;
}

// ---------------------------------------------------------------------------
// x row -> D_m, qx = rint(x/D_m) (main) + gathered correction cols (fused).
// ---------------------------------------------------------------------------
__global__ void quant_x_kernel(const float4* __restrict__ x4,
                               const int* __restrict__ idx,
                               signed char* __restrict__ qx,
                               float* __restrict__ rdel,
                               int IC, int K2, int n_out) {
    __shared__ float red[4];
    __shared__ float bmax;
    __shared__ signed char rowq[4096];
    const int m = blockIdx.x;
    const int t = threadIdx.x;
    const int lane = t & 63, wid = t >> 6;

    const float4* row4 = x4 + (size_t)m * (IC / 4);
    float4 v[4];
    float mx = 0.f;
#pragma unroll
    for (int j = 0; j < 4; ++j) {
        v[j] = row4[t + j * 256];
        mx = fmaxf(mx, fmaxf(fmaxf(fabsf(v[j].x), fabsf(v[j].y)),
                             fmaxf(fabsf(v[j].z), fabsf(v[j].w))));
    }
#pragma unroll
    for (int off = 32; off; off >>= 1) mx = fmaxf(mx, __shfl_down(mx, off));
    if (lane == 0) red[wid] = mx;
    __syncthreads();
    if (t == 0) {
        float m0 = fmaxf(fmaxf(red[0], red[1]), fmaxf(red[2], red[3]));
        bmax = m0;
        rdel[m] = m0 / 127.f;
    }
    __syncthreads();
    const float inv = 127.f / bmax;

    const size_t base = (size_t)m * K2;
#pragma unroll
    for (int j = 0; j < 4; ++j) {
        const int c0 = (t + j * 256) * 4;
        float ee[4] = {v[j].x, v[j].y, v[j].z, v[j].w};
        int pack = 0;
#pragma unroll
        for (int ei = 0; ei < 4; ++ei) {
            int q = (int)rintf(ee[ei] * inv);
            pack |= (q & 0xff) << (ei * 8);
        }
        *(int*)(qx + base + c0) = pack;
        *(int*)(rowq + c0) = pack;
    }
    __syncthreads();

    signed char g = 0;
    if (t < n_out) g = rowq[idx[t]];
    qx[base + IC + t] = g;
}

// ---------------------------------------------------------------------------
// i8 GEMM: acc[m,o] = sum_k qx[m,k]*qw[o,k]; out = acc*(s_o*D_m/8) + bias.
// 512 thr = 8 waves (2M x 4N), per-wave 128x64 = 8(mi) x 4(ni) frags 16x16,
// mfma_i32_16x16x64_i8. LDS: 4 bufs x 32 KB, slot-XOR swizzle (0 conflicts).
// Shadow-read tile body (1 barrier/tile):
//   STAGE(t+3) ; vmcnt(8) [drains t+1's stages: 12 outstanding -> 8] ;
//   barrier [cross-thread visibility of buf t+1] ;
//   setprio(1) ; 32 MFMA(t) [regs read in tile t-1's shadow] ; setprio(0) ;
//   RDB+RDA0+RDA1 of tile t+1 [12 ds_reads complete under MFMA drain]
// WAR: reads(t+1) < MFMA(t+1) < barrier(t+2) < stage(t+5) overwriting
// buf t+1. Reg WAR: MFMA consumes operands at issue; reads reuse same regs.
// ---------------------------------------------------------------------------
#define GLDS(src, dst) __builtin_amdgcn_global_load_lds( \
    (const __attribute__((address_space(1))) void*)(src), \
    (__attribute__((address_space(3))) void*)(dst), 16, 0, 0)

// Stage matrix MAT (0=A,1=B) of the BK64 tile at byte k-offset knB into bufS.
#define STAGE64(MAT, bufS, knB) do {                                          \
    const signed char* gsrc_ = (MAT) ? Bblk : Ablk;                           \
    _Pragma("unroll")                                                         \
    for (int rr_ = 0; rr_ < 2; ++rr_) {                                       \
      GLDS(gsrc_ + (size_t)(rr_ * 128 + stg_row) * K2 + (knB) + stg_col,      \
           &ldsb[(bufS) * 32768 + (MAT) * 16384 + (rr_ * 128 + wid * 16) * 64]); \
    } } while (0)

// A-fragment reads (4 x ds_read_b128) for fragment-half FH from buf B_
#define RDA(AF, FH, B_) do {                                                  \
    const signed char* pa_ = &ldsb[(B_) * 32768];                             \
    _Pragma("unroll")                                                         \
    for (int j_ = 0; j_ < 4; ++j_)                                            \
      AF[j_] = *(const i32x4*)&pa_[(wr * 128 + ((FH) * 4 + j_) * 16 + l15) * 64 + slB]; \
  } while (0)

// B-fragment reads (4 x ds_read_b128) from buf B_
#define RDB(BF, B_) do {                                                      \
    const signed char* pb_ = &ldsb[(B_) * 32768 + 16384];                     \
    _Pragma("unroll")                                                         \
    for (int j_ = 0; j_ < 4; ++j_)                                            \
      BF[j_] = *(const i32x4*)&pb_[(wc * 64 + j_ * 16 + l15) * 64 + slB];     \
  } while (0)

#define MM16(AF, FH) do {                                                     \
    _Pragma("unroll")                                                         \
    for (int mi_ = 0; mi_ < 4; ++mi_)                                         \
      _Pragma("unroll")                                                       \
      for (int ni_ = 0; ni_ < 4; ++ni_)                                       \
        acc[(FH) * 4 + mi_][ni_] = __builtin_amdgcn_mfma_i32_16x16x64_i8(     \
            AF[mi_], bfr[ni_], acc[(FH) * 4 + mi_][ni_], 0, 0, 0);            \
  } while (0)

// One K-tile: stage t+3 -> bufS, fence+barrier, MFMA tile t (preloaded regs),
// then read tile t+1's fragments from bufN in the MFMA shadow.
#define KT64(bufN, bufS, knB) do {                                            \
    STAGE64(0, bufS, knB);                                                    \
    STAGE64(1, bufS, knB);                                                    \
    asm volatile("s_waitcnt vmcnt(8)" ::: "memory");                          \
    __builtin_amdgcn_s_barrier();                                             \
    __builtin_amdgcn_s_setprio(1);                                            \
    MM16(afr0, 0);                                                            \
    MM16(afr1, 1);                                                            \
    __builtin_amdgcn_s_setprio(0);                                            \
    RDB(bfr, bufN);                                                           \
    RDA(afr0, 0, bufN);                                                       \
    RDA(afr1, 1, bufN);                                                       \
  } while (0)

__global__ __launch_bounds__(512, 2) void gemm_i8_kernel(
    const signed char* __restrict__ Aq,   // [M, K2] i8
    const signed char* __restrict__ Bq,   // [OC, K2] i8
    const float* __restrict__ bias,       // [OC]
    const float* __restrict__ sArr,       // [OC]
    const float* __restrict__ rdel,       // [M]
    float* __restrict__ C,                // [M, OC] f32
    int M, int N, int K2, int NBN) {
    extern __shared__ signed char ldsb[];  // 131072 B = 4 x 32 KiB buffers

    const int t = threadIdx.x;
    const int wid = t >> 6, lane = t & 63;
    const int l15 = lane & 15;
    const int slB = (((lane >> 4) ^ ((lane >> 1) & 3)) & 3) * 16;  // read slot
    const int wr = wid >> 2;                  // 0..1  (M half)
    const int wc = wid & 3;                   // 0..3  (N quarter)
    const int stg_row = wid * 16 + (lane >> 2);
    const int stg_col = (((lane & 3) ^ ((lane >> 3) & 3)) & 3) * 16;  // bytes

    // bijective XCD swizzle
    const int nwg = gridDim.x;
    const int bid = blockIdx.x;
    const int q = nwg >> 3, r = nwg & 7;
    const int xcd = bid & 7, off = bid >> 3;
    const int swz = (xcd < r ? xcd * (q + 1) : r * (q + 1) + (xcd - r) * q) + off;
    const int bm = swz / NBN, bn = swz % NBN;

    const signed char* Ablk = Aq + (size_t)(bm * 256) * K2;
    const signed char* Bblk = Bq + (size_t)(bn * 256) * K2;

    i32x4 acc[8][4] = {};
    i32x4 afr0[4], afr1[4], bfr[4];

    // ---- prologue: stage tiles 0,1,2 -> bufs 0,1,2; drain tile0;
    //      pre-read tile0's fragments ----
    STAGE64(0, 0, 0);    STAGE64(1, 0, 0);
    STAGE64(0, 1, 64);   STAGE64(1, 1, 64);
    STAGE64(0, 2, 128);  STAGE64(1, 2, 128);
    asm volatile("s_waitcnt vmcnt(8)" ::: "memory");
    __builtin_amdgcn_s_barrier();
    RDB(bfr, 0);
    RDA(afr0, 0, 0);
    RDA(afr1, 1, 0);

    // NT = K2/64 = 68 tiles = 17 iterations x 4. Tile t: stage t+3 into
    // (t+3)%4, MFMA t (preloaded), shadow-read t+1 from (t+1)%4.
    // Tail: dead stages (kn=0) and one dead read (t=67 reads buf0 garbage,
    // never consumed) -- all in-bounds.
    for (int it = 0; it < 17; ++it) {
        const int tt = it * 4;
        const int k3 = (tt + 3) * 64;                        // <= 67*64, live
        const int k4 = (tt + 4 < 68) ? (tt + 4) * 64 : 0;    // dead at end
        const int k5 = (tt + 5 < 68) ? (tt + 5) * 64 : 0;
        const int k6 = (tt + 6 < 68) ? (tt + 6) * 64 : 0;
        KT64(1, 3, k3);
        KT64(2, 0, k4);
        KT64(3, 1, k5);
        KT64(0, 2, k6);
    }

    // ---- epilogue: out = acc*(s_o*D_m/8) + bias ----
    // C/D layout: col = lane&15, row = (lane>>4)*4 + reg
    float sv[4], bv[4];
#pragma unroll
    for (int ni = 0; ni < 4; ++ni) {
        const int col = bn * 256 + wc * 64 + ni * 16 + l15;
        sv[ni] = sArr[col] * 0.125f;
        bv[ni] = bias[col];
    }

    const int crow0 = bm * 256 + wr * 128;
    const int ccol = bn * 256 + wc * 64 + l15;
#pragma unroll
    for (int mi = 0; mi < 8; ++mi) {
#pragma unroll
        for (int rr = 0; rr < 4; ++rr) {
            const int row = crow0 + mi * 16 + (lane >> 4) * 4 + rr;
            const float rd = rdel[row];
            float* Crow = C + (size_t)row * N;
#pragma unroll
            for (int ni = 0; ni < 4; ++ni)
                Crow[ccol + ni * 16] =
                    (float)acc[mi][ni][rr] * (sv[ni] * rd) + bv[ni];
        }
    }
}

// ---------------------------------------------------------------------------
extern "C" void kernel_launch(void* const* d_in, const int* in_sizes, int n_in,
                              void* d_out, int out_size, void* d_ws, size_t ws_size,
                              hipStream_t stream) {
    const float* x      = (const float*)d_in[0];
    const float* weight = (const float*)d_in[1];
    const float* bias   = (const float*)d_in[2];
    const float* ow     = (const float*)d_in[3];
    const int*   idx    = (const int*)d_in[4];

    const int OC    = in_sizes[2];
    const int n_out = in_sizes[4];
    const int IC    = in_sizes[1] / OC;      // 4096
    const int M     = in_sizes[0] / IC;      // 8192
    const int K2    = IC + 256;              // 4352
    float* out = (float*)d_out;

    char* ws = (char*)d_ws;
    signed char* qx = (signed char*)ws;                                 // M*K2
    signed char* qw = (signed char*)(ws + (size_t)M * K2);              // OC*K2
    float* sArr = (float*)(ws + (size_t)M * K2 + (size_t)OC * K2);      // OC
    float* rdel = sArr + OC;                                            // M

    quant_sign_kernel<<<OC, 256, 0, stream>>>(weight, ow, idx, qw, sArr,
                                              IC, K2, n_out);
    quant_x_kernel<<<M, 256, 0, stream>>>((const float4*)x, idx, qx, rdel,
                                          IC, K2, n_out);

    hipFuncSetAttribute((const void*)gemm_i8_kernel,
                        hipFuncAttributeMaxDynamicSharedMemorySize, 131072);
    const int NBM = M / 256, NBN = OC / 256;
    gemm_i8_kernel<<<dim3(NBM * NBN), dim3(512), 131072, stream>>>(
        qx, qw, bias, sArr, rdel, out, M, OC, K2, NBN);
}